// Round 2
// baseline (535.883 us; speedup 1.0000x reference)
//
#include <hip/hip_runtime.h>

#define PI_F 3.14159265358979323846f

template<int v> struct ic_t { static constexpr int value = v; };

template<int N, int I = 0, typename F>
__device__ __forceinline__ void sfor(F&& f) {
  if constexpr (I < N) { f(ic_t<I>{}); sfor<N, I + 1>(static_cast<F&&>(f)); }
}

__host__ __device__ constexpr int fold_idx(int t) {
  t &= 63;
  return (t <= 16) ? t : (t <= 32) ? (32 - t) : (t <= 48) ? (t - 32) : (64 - t);
}
__host__ __device__ constexpr float fold_sgn(int t) {
  t &= 63;
  return (t <= 16) ? 1.f : (t <= 48) ? -1.f : 1.f;
}

// cos/sin(2*pi*T/64) from register table cc[17]; T must be compile-time.
#define TCOS(T) (fold_sgn(T) * cc[fold_idx(T)])
#define TSIN(T) (fold_sgn(((T) + 48) & 63) * cc[fold_idx(((T) + 48) & 63)])

// ---------------------------------------------------------------------------
// Kernel 1: forward low-mode DFT, transposed order (n0 -> n1 -> n2) so that
// lanes map to the contiguous n2 axis: every global load is 64 consecutive
// floats (fully coalesced). grid 2048 = {q,k} x (b*H+h)*E+e, block 256.
//   phase 1 (per n1): A[k0] = sum_n0 x[n0,n1,lane] e^{-2pi i k0 n0/32}  (radix-2 fold)
//   phase 2: B[k1][k0] += A * e^{-2pi i k1 n1/32}   (regs, streamed over n1 chunks)
//   phase 3: out[k0,k1,k2] = sum_n2 B e^{-2pi i k2 n2/64} (1 wave, radix-2 fold)
// LDS ~33.6 KB -> 4 blocks/CU = 16 waves/CU.
// ---------------------------------------------------------------------------
__global__ __launch_bounds__(256, 4)
void k1_fwd_dft(const float* __restrict__ qg, const float* __restrict__ kg,
                float2* __restrict__ qsel, float2* __restrict__ ksel)
{
  // Abuf serves two roles (separated by barriers):
  //  - chunks: A[n1loc<8][k0<8][n2<64]  (4096 float2, contiguous)
  //  - final:  Btile[row<64][n2 pad 65] (4160 float2)
  __shared__ float2 Abuf[64 * 65];
  __shared__ float2 tw32[32];     // (cos, sin)(2*pi*t/32)

  const int tid = threadIdx.x;
  const int lane = tid & 63;       // n2 index
  const int wv = tid >> 6;         // 0..3
  const int bid = blockIdx.x;
  const int t1023 = bid & 1023;
  const float* __restrict__ src = (bid < 1024 ? qg : kg) + (size_t)t1023 * 65536;
  float2* __restrict__ dst = (bid < 1024 ? qsel : ksel) + t1023 * 512;

  float cc[17];
  sfor<17>([&](auto J) { constexpr int j = decltype(J)::value;
    cc[j] = cosf((float)j * (PI_F / 32.f)); });

  if (tid < 32) {
    float s, c;
    sincosf((float)tid * (2.f * PI_F / 32.f), &s, &c);
    tw32[tid] = make_float2(c, s);
  }

  float Br[2][8], Bi[2][8];
  sfor<2>([&](auto J) { constexpr int j = decltype(J)::value;
    sfor<8>([&](auto K) { constexpr int k = decltype(K)::value;
      Br[j][k] = 0.f; Bi[j][k] = 0.f; }); });

  sfor<4>([&](auto CH) {
    constexpr int chunk = decltype(CH)::value;
    // ---- phase 1: this wave computes n1 = chunk*8 + wv*2 + {0,1}
    sfor<2>([&](auto JC) {
      constexpr int j = decltype(JC)::value;
      const int n1 = chunk * 8 + wv * 2 + j;
      const float* __restrict__ rp = src + n1 * 64 + lane;
      float accR[8], accI[8];
      sfor<8>([&](auto K) { constexpr int k = decltype(K)::value;
        accR[k] = 0.f; accI[k] = 0.f; });
      sfor<16>([&](auto NP) {
        constexpr int n0p = decltype(NP)::value;
        const float a = rp[n0p * 2048];
        const float b = rp[(n0p + 16) * 2048];
        const float s = a + b;
        const float d = a - b;
        sfor<8>([&](auto KC) {
          constexpr int k0 = decltype(KC)::value;
          constexpr int t = (2 * k0 * n0p) & 63;
          const float g = ((k0 & 1) == 0) ? s : d;
          accR[k0] = fmaf(g,  TCOS(t), accR[k0]);
          accI[k0] = fmaf(-g, TSIN(t), accI[k0]);
        });
      });
      const int abase = (wv * 2 + j) * 8 * 64 + lane;
      sfor<8>([&](auto KC) {
        constexpr int k0 = decltype(KC)::value;
        Abuf[abase + k0 * 64] = make_float2(accR[k0], accI[k0]);
      });
    });
    __syncthreads();
    // ---- phase 2: this wave owns k1 = wv*2 + {0,1}; accumulate B in regs
    sfor<2>([&](auto JC) {
      constexpr int j = decltype(JC)::value;
      const int k1 = wv * 2 + j;
      sfor<8>([&](auto NL) {
        constexpr int n1loc = decltype(NL)::value;
        constexpr int n1 = chunk * 8 + n1loc;
        const float2 tw = tw32[(k1 * n1) & 31];   // wave-uniform -> broadcast
        sfor<8>([&](auto KC) {
          constexpr int k0 = decltype(KC)::value;
          const float2 a = Abuf[(n1loc * 8 + k0) * 64 + lane];
          Br[j][k0] = fmaf(a.x, tw.x, fmaf( a.y, tw.y, Br[j][k0]));
          Bi[j][k0] = fmaf(a.y, tw.x, fmaf(-a.x, tw.y, Bi[j][k0]));
        });
      });
    });
    __syncthreads();   // before next chunk's phase 1 overwrites Abuf
  });

  // ---- write B to padded tile: row = k1*8+k0, stride 65 (2-way max)
  sfor<2>([&](auto JC) {
    constexpr int j = decltype(JC)::value;
    sfor<8>([&](auto KC) {
      constexpr int k0 = decltype(KC)::value;
      Abuf[((wv * 2 + j) * 8 + k0) * 65 + lane] = make_float2(Br[j][k0], Bi[j][k0]);
    });
  });
  __syncthreads();

  // ---- phase 3: one wave, lane = row = k1*8+k0; n2 DFT with radix-2 fold
  if (tid < 64) {
    const float2* __restrict__ rb = &Abuf[tid * 65];
    float oR[8], oI[8];
    sfor<8>([&](auto K) { constexpr int k = decltype(K)::value;
      oR[k] = 0.f; oI[k] = 0.f; });
    sfor<32>([&](auto MC) {
      constexpr int m = decltype(MC)::value;
      const float2 p = rb[m];
      const float2 q = rb[m + 32];
      const float sx = p.x + q.x, sy = p.y + q.y;
      const float dx = p.x - q.x, dy = p.y - q.y;
      sfor<8>([&](auto KC) {
        constexpr int k2 = decltype(KC)::value;
        constexpr int t = (k2 * m) & 63;
        const float gx = ((k2 & 1) == 0) ? sx : dx;
        const float gy = ((k2 & 1) == 0) ? sy : dy;
        oR[k2] = fmaf(gx, TCOS(t), fmaf( gy, TSIN(t), oR[k2]));
        oI[k2] = fmaf(gy, TCOS(t), fmaf(-gx, TSIN(t), oI[k2]));
      });
    });
    const int k1 = tid >> 3, k0 = tid & 7;
    sfor<8>([&](auto KC) {
      constexpr int k2 = decltype(KC)::value;
      dst[(k0 << 6) + (k1 << 3) + k2] =
          make_float2(oR[k2] * (1.f / 256.f), oI[k2] * (1.f / 256.f));
    });
  }
}

// ---------------------------------------------------------------------------
// Kernel 2: fused complex attention  xqkv[e,x] = sum_y tanh(sum_e' Q K) * K.
// grid 512 = (b*H+h)*8 + xo; block 512 = 64 x-rows * 8 y-groups (64 y each).
// 2 blocks/CU (64 KB K tile) * 8 waves = 50% occupancy.
// ---------------------------------------------------------------------------
__global__ __launch_bounds__(512, 4)
void k2_attn(const float2* __restrict__ qsel, const float2* __restrict__ ksel,
             float2* __restrict__ xqkv)
{
  __shared__ float2 Kl[8192];   // [e<16][y<512], reused as reduction buffer
  const int tid = threadIdx.x;
  const int bh = blockIdx.x >> 3;
  const int xo = blockIdx.x & 7;

  const float2* __restrict__ kb = ksel + bh * 8192;
  for (int i = tid; i < 8192; i += 512) Kl[i] = kb[i];

  const int xr = tid & 63;
  const int yh = tid >> 6;           // 0..7
  const int x = xo * 64 + xr;
  const float2* __restrict__ qb = qsel + bh * 8192;
  float qr[16], qi[16], ar[16], ai[16];
  sfor<16>([&](auto E) {
    constexpr int e = decltype(E)::value;
    const float2 v = qb[e * 512 + x];
    qr[e] = v.x; qi[e] = v.y;
    ar[e] = 0.f; ai[e] = 0.f;
  });
  __syncthreads();

  const int y0 = yh * 64;
  for (int y = y0; y < y0 + 64; ++y) {
    float kr[16], ki[16];
    float sr = 0.f, si = 0.f;
    sfor<16>([&](auto E) {
      constexpr int e = decltype(E)::value;
      const float2 v = Kl[e * 512 + y];      // wave-uniform -> broadcast
      kr[e] = v.x; ki[e] = v.y;
      sr = fmaf(qr[e], v.x, fmaf(-qi[e], v.y, sr));
      si = fmaf(qr[e], v.y, fmaf( qi[e], v.x, si));
    });
    // complex tanh(sr + i si) = (sinh 2a + i sin 2b) / (cosh 2a + cos 2b)
    float a2 = 2.f * sr;
    a2 = fminf(fmaxf(a2, -30.f), 30.f);
    const float b2 = 2.f * si;
    const float ea = expf(a2);
    const float ei = 1.f / ea;
    const float sh = 0.5f * (ea - ei);
    const float chp = 0.5f * (ea + ei);
    float sb, cb;
    sincosf(b2, &sb, &cb);
    const float inv = 1.f / (chp + cb);
    const float tr = sh * inv;
    const float ti = sb * inv;
    sfor<16>([&](auto E) {
      constexpr int e = decltype(E)::value;
      ar[e] = fmaf(tr, kr[e], fmaf(-ti, ki[e], ar[e]));
      ai[e] = fmaf(tr, ki[e], fmaf( ti, kr[e], ai[e]));
    });
  }
  __syncthreads();
  float* __restrict__ red = (float*)Kl;   // K dead; 16384 floats available
  if (yh) {
    const int g = yh - 1;                 // 0..6, 7*32*64 = 14336 floats
    sfor<16>([&](auto E) {
      constexpr int e = decltype(E)::value;
      red[(g * 32 + 2 * e) * 64 + xr] = ar[e];
      red[(g * 32 + 2 * e + 1) * 64 + xr] = ai[e];
    });
  }
  __syncthreads();
  if (!yh) {
    float2* __restrict__ ob = xqkv + bh * 8192;
    sfor<16>([&](auto E) {
      constexpr int e = decltype(E)::value;
      float sr2 = ar[e], si2 = ai[e];
      #pragma unroll
      for (int g = 0; g < 7; ++g) {
        sr2 += red[(g * 32 + 2 * e) * 64 + xr];
        si2 += red[(g * 32 + 2 * e + 1) * 64 + xr];
      }
      ob[e * 512 + x] = make_float2(sr2, si2);
    });
  }
}

// ---------------------------------------------------------------------------
// Kernel 3: w-multiply + analytic canonicalized inverse transform.
// out = (1/2^22) * sum_{k} w2(k2) cos(2pi k2 n2/64) * Re[F e^{i 2pi(k0n0+k1n1)/32}]
// grid 1024 = (b,h,o); block 256. Separable: A over k2, B over k1, C over k0.
// ---------------------------------------------------------------------------
#define SCALE_OUT (1.f / 4194304.f)

__global__ __launch_bounds__(256, 2)
void k3_inv(const float2* __restrict__ xqkv, const float* __restrict__ w_re,
            const float* __restrict__ w_im, float* __restrict__ out)
{
  __shared__ float2 Fs[512];
  __shared__ float cn[64];                   // cos(2*pi*t/64)
  __shared__ float Ur[4096], Ui[4096];       // [p=k0*8+k1][n2]
  __shared__ float Vr[2048], Vi[2048];       // [k0*4+n1loc][n2], 4-n1 chunks

  const int tid = threadIdx.x;
  const int bho = blockIdx.x;
  const int o = bho & 15;
  const int h = (bho >> 4) & 7;
  const int bh = bho >> 4;                   // b*8+h

  if (tid < 64) cn[tid] = cosf((float)tid * (PI_F / 32.f));

  float cc[17];
  sfor<17>([&](auto J) { constexpr int j = decltype(J)::value;
    cc[j] = cosf((float)j * (PI_F / 32.f)); });

  // F[x] = sum_e xqkv[e,x] * w[e,o,x], scaled
  const float2* __restrict__ xb = xqkv + bh * 8192;
  const float* __restrict__ wrb = w_re + ((size_t)(h * 256 + o)) * 512;
  const float* __restrict__ wib = w_im + ((size_t)(h * 256 + o)) * 512;
  for (int x = tid; x < 512; x += 256) {
    float fr = 0.f, fi = 0.f;
    sfor<16>([&](auto E) {
      constexpr int e = decltype(E)::value;
      const float2 v = xb[e * 512 + x];
      const float wr = wrb[e * 8192 + x];
      const float wi = wib[e * 8192 + x];
      fr = fmaf(v.x, wr, fmaf(-v.y, wi, fr));
      fi = fmaf(v.x, wi, fmaf( v.y, wr, fi));
    });
    Fs[x] = make_float2(fr * SCALE_OUT, fi * SCALE_OUT);
  }
  __syncthreads();

  const int n2 = tid & 63;
  const int wv = tid >> 6;

  // stage A: U[p][n2] = sum_k2 w2(k2) cos(2pi k2 n2/64) F[p*8+k2]
  #pragma unroll
  for (int i = 0; i < 16; ++i) {
    const int p = wv * 16 + i;
    float ur = 0.f, ui = 0.f;
    sfor<8>([&](auto KC) {
      constexpr int k2 = decltype(KC)::value;
      const float2 f = Fs[p * 8 + k2];       // wave-uniform broadcast
      const float cv = cn[(k2 * n2) & 63];
      const float wgt = (k2 == 0) ? cv : 2.f * cv;
      ur = fmaf(wgt, f.x, ur);
      ui = fmaf(wgt, f.y, ui);
    });
    Ur[p * 64 + n2] = ur;
    Ui[p * 64 + n2] = ui;
  }
  __syncthreads();

  // per-thread U registers for its two k0 columns
  float u_r[2][8], u_i[2][8];
  sfor<2>([&](auto JC) {
    constexpr int j = decltype(JC)::value;
    sfor<8>([&](auto KC) {
      constexpr int k1 = decltype(KC)::value;
      const int p = (wv * 2 + j) * 8 + k1;
      u_r[j][k1] = Ur[p * 64 + n2];
      u_i[j][k1] = Ui[p * 64 + n2];
    });
  });

  float* __restrict__ ob = out + (size_t)bho * 65536;

  for (int chq = 0; chq < 8; ++chq) {        // 4 n1 values per chunk
    // stage B: V[k0][n1loc][n2] = sum_k1 U * e^{+i 2pi k1 n1/32}
    sfor<2>([&](auto JC) {
      constexpr int j = decltype(JC)::value;
      const int k0 = wv * 2 + j;
      sfor<4>([&](auto LC) {
        constexpr int l = decltype(LC)::value;
        const int n1 = chq * 4 + l;
        float vr = 0.f, vi = 0.f;
        sfor<8>([&](auto KC) {
          constexpr int k1 = decltype(KC)::value;
          const int t = (2 * k1 * n1) & 63;  // wave-uniform -> broadcast reads
          const float cv = cn[t];
          const float sv = cn[(t + 48) & 63];
          vr = fmaf(u_r[j][k1], cv, fmaf(-u_i[j][k1], sv, vr));
          vi = fmaf(u_r[j][k1], sv, fmaf( u_i[j][k1], cv, vi));
        });
        Vr[(k0 * 4 + l) * 64 + n2] = vr;
        Vi[(k0 * 4 + l) * 64 + n2] = vi;
      });
    });
    __syncthreads();
    // stage C: out[n0][n1][n2] = sum_k0 Vr cos - Vi sin   (literal twiddles)
    {
      const int l = wv;
      float vrr[8], vii[8];
      sfor<8>([&](auto KC) {
        constexpr int k0 = decltype(KC)::value;
        vrr[k0] = Vr[(k0 * 4 + l) * 64 + n2];
        vii[k0] = Vi[(k0 * 4 + l) * 64 + n2];
      });
      const int n1 = chq * 4 + l;
      float* __restrict__ op = ob + n1 * 64 + n2;
      sfor<32>([&](auto NC) {
        constexpr int n0 = decltype(NC)::value;
        float acc = vrr[0];
        sfor<7>([&](auto KC) {
          constexpr int k0 = decltype(KC)::value + 1;
          constexpr int t = (2 * k0 * n0) & 63;
          acc = fmaf(vrr[k0], TCOS(t), fmaf(-vii[k0], TSIN(t), acc));
        });
        op[n0 * 2048] = acc;
      });
    }
    __syncthreads();
  }
}

// ---------------------------------------------------------------------------
extern "C" void kernel_launch(void* const* d_in, const int* in_sizes, int n_in,
                              void* d_out, int out_size, void* d_ws, size_t ws_size,
                              hipStream_t stream)
{
  (void)in_sizes; (void)n_in; (void)out_size; (void)ws_size;
  const float* q    = (const float*)d_in[0];
  const float* k    = (const float*)d_in[1];
  const float* w_re = (const float*)d_in[2];
  const float* w_im = (const float*)d_in[3];
  float* out = (float*)d_out;

  // workspace: qsel(4MB) | ksel(4MB) | xqkv(4MB), all [bh][e][x] float2
  float2* qsel = (float2*)d_ws;
  float2* ksel = qsel + 1024 * 512;
  float2* xqkv = ksel + 1024 * 512;

  hipLaunchKernelGGL(k1_fwd_dft, dim3(2048), dim3(256), 0, stream, q, k, qsel, ksel);
  hipLaunchKernelGGL(k2_attn,    dim3(512),  dim3(512), 0, stream, qsel, ksel, xqkv);
  hipLaunchKernelGGL(k3_inv,     dim3(1024), dim3(256), 0, stream, xqkv, w_re, w_im, out);
}

// Round 4
// 327.231 us; speedup vs baseline: 1.6376x; 1.6376x over previous
//
#include <hip/hip_runtime.h>

#define PI_F 3.14159265358979323846f

template<int v> struct ic_t { static constexpr int value = v; };

template<int N, int I = 0, typename F>
__device__ __forceinline__ void sfor(F&& f) {
  if constexpr (I < N) { f(ic_t<I>{}); sfor<N, I + 1>(static_cast<F&&>(f)); }
}

__host__ __device__ constexpr int fold_idx(int t) {
  t &= 63;
  return (t <= 16) ? t : (t <= 32) ? (32 - t) : (t <= 48) ? (t - 32) : (64 - t);
}
__host__ __device__ constexpr float fold_sgn(int t) {
  t &= 63;
  return (t <= 16) ? 1.f : (t <= 48) ? -1.f : 1.f;
}

// cos(k*pi/32), k=0..16, f32-rounded literals (compile-time only -> 0 VGPRs).
__device__ constexpr float CCV[17] = {
  1.0f, 0.9951847266721969f, 0.9807852804032304f, 0.9569403357322088f,
  0.9238795325112867f, 0.8819212643483550f, 0.8314696123025452f,
  0.7730104533627370f, 0.7071067811865476f, 0.6343932841636455f,
  0.5555702330196022f, 0.4713967368259976f, 0.3826834323650898f,
  0.2902846772544623f, 0.1950903220161283f, 0.0980171403295606f, 0.0f};

// cos/sin(2*pi*T/64); T must be compile-time -> folds to a literal constant.
#define TCOS(T) (fold_sgn(T) * CCV[fold_idx(T)])
#define TSIN(T) (fold_sgn(((T) + 48) & 63) * CCV[fold_idx(((T) + 48) & 63)])

// ---------------------------------------------------------------------------
// Kernel 1: forward low-mode DFT, transposed order (n0 -> n1 -> n2), float2
// coalesced loads, engineered against spills (peak ~70 VGPR, literal twiddles).
// grid 2048 = {q,k} x (b*H+h)*E+e, block 512 (8 waves).
//   phase 1: per (n1, n2-pair): A[k0] = radix-2-folded 32-pt DFT over n0
//   phase 2: wave wv owns k1=wv: Br/Bi[k0] += A * e^{-2pi i k1 n1/32}  (regs)
//   phase 3: wave wv owns k2=wv, lane=row: 64-pt DFT over n2 from LDS B-tile
// LDS 64.5 KB -> 2 blocks/CU = 16 waves/CU.
// ---------------------------------------------------------------------------
__global__ __launch_bounds__(512)
void k1_fwd_dft(const float* __restrict__ qg, const float* __restrict__ kg,
                float2* __restrict__ qsel, float2* __restrict__ ksel)
{
  __shared__ float2 A[8192];     // chunks: A[n1loc<16][k0<8][n2<64]; end: Bt[64][65]
  __shared__ float2 tw64[64];    // (cos,sin)(2*pi*t/64)

  const int tid = threadIdx.x;
  const int lane = tid & 63;
  const int wv = tid >> 6;                  // 0..7
  const int bid = blockIdx.x;
  const int t1023 = bid & 1023;
  const float* __restrict__ src = (bid < 1024 ? qg : kg) + (size_t)t1023 * 65536;
  float2* __restrict__ dst = (bid < 1024 ? qsel : ksel) + t1023 * 512;

  if (tid < 64) {
    float s, c;
    sincosf((float)tid * (2.f * PI_F / 64.f), &s, &c);
    tw64[tid] = make_float2(c, s);
  }

  const int n1b = wv * 2 + (lane >> 5);     // 0..15 within a 16-n1 chunk
  const int n2h = lane & 31;                // float2 column (n2 = 2*n2h+{0,1})
  const float2* __restrict__ sp = (const float2*)src + n1b * 32 + n2h;

  float Br[8], Bi[8];
  sfor<8>([&](auto K) { constexpr int k = decltype(K)::value;
    Br[k] = 0.f; Bi[k] = 0.f; });

  sfor<2>([&](auto CH) {
    constexpr int chunk = decltype(CH)::value;
    // ---- phase 1: 32-pt DFT over n0 (radix-2 fold), 2 n2 values per thread
    float aR[2][8], aI[2][8];
    sfor<8>([&](auto K) { constexpr int k = decltype(K)::value;
      aR[0][k] = 0.f; aI[0][k] = 0.f; aR[1][k] = 0.f; aI[1][k] = 0.f; });
    const float2* __restrict__ spc = sp + chunk * 512;
    sfor<16>([&](auto NP) {
      constexpr int n0p = decltype(NP)::value;
      const float2 a = spc[n0p * 1024];
      const float2 b = spc[(n0p + 16) * 1024];
      const float sx = a.x + b.x, sy = a.y + b.y;
      const float dx = a.x - b.x, dy = a.y - b.y;
      sfor<8>([&](auto KC) {
        constexpr int k0 = decltype(KC)::value;
        constexpr int t = (2 * k0 * n0p) & 63;
        const float gx = (k0 & 1) ? dx : sx;
        const float gy = (k0 & 1) ? dy : sy;
        aR[0][k0] = fmaf(gx,  TCOS(t), aR[0][k0]);
        aI[0][k0] = fmaf(-gx, TSIN(t), aI[0][k0]);
        aR[1][k0] = fmaf(gy,  TCOS(t), aR[1][k0]);
        aI[1][k0] = fmaf(-gy, TSIN(t), aI[1][k0]);
      });
    });
    sfor<8>([&](auto KC) {
      constexpr int k0 = decltype(KC)::value;
      float4* p = (float4*)&A[(n1b * 8 + k0) * 64 + 2 * n2h];
      *p = make_float4(aR[0][k0], aI[0][k0], aR[1][k0], aI[1][k0]);
    });
    __syncthreads();
    // ---- phase 2: wave wv = k1; accumulate B over the chunk's 16 n1
    sfor<16>([&](auto NL) {
      constexpr int n1l = decltype(NL)::value;
      const int tt = (2 * wv * (chunk * 16 + n1l)) & 63;   // wave-uniform
      const float2 w = tw64[tt];                            // LDS broadcast
      sfor<8>([&](auto KC) {
        constexpr int k0 = decltype(KC)::value;
        const float2 a = A[(n1l * 8 + k0) * 64 + lane];
        Br[k0] = fmaf(a.x, w.x, fmaf( a.y, w.y, Br[k0]));
        Bi[k0] = fmaf(a.y, w.x, fmaf(-a.x, w.y, Bi[k0]));
      });
    });
    __syncthreads();   // before next chunk's phase 1 overwrites A
  });

  // ---- write B tile: row = k1*8+k0, stride 65 (2-way max on read-back)
  sfor<8>([&](auto KC) {
    constexpr int k0 = decltype(KC)::value;
    A[(wv * 8 + k0) * 65 + lane] = make_float2(Br[k0], Bi[k0]);
  });
  __syncthreads();

  // ---- phase 3: wave wv = k2, lane = row = k1*8+k0; 64-pt DFT over n2
  {
    const float2* __restrict__ rb = &A[lane * 65];
    float oR = 0.f, oI = 0.f;
    #pragma unroll 8
    for (int n2 = 0; n2 < 64; ++n2) {
      const float2 b = rb[n2];
      const float2 w = tw64[(wv * n2) & 63];   // wave-uniform broadcast
      oR = fmaf(b.x, w.x, fmaf( b.y, w.y, oR));
      oI = fmaf(b.y, w.x, fmaf(-b.x, w.y, oI));
    }
    dst[((lane & 7) << 6) + ((lane >> 3) << 3) + wv] =
        make_float2(oR * (1.f / 256.f), oI * (1.f / 256.f));
  }
}

// ---------------------------------------------------------------------------
// Kernel 2: fused complex attention  xqkv[e,x] = sum_y tanh(sum_e' Q K) * K.
// grid 512 = (b*H+h)*8 + xo; block 512 = 64 x-rows * 8 y-groups (64 y each).
// ---------------------------------------------------------------------------
__global__ __launch_bounds__(512, 4)
void k2_attn(const float2* __restrict__ qsel, const float2* __restrict__ ksel,
             float2* __restrict__ xqkv)
{
  __shared__ float2 Kl[8192];   // [e<16][y<512], reused as reduction buffer
  const int tid = threadIdx.x;
  const int bh = blockIdx.x >> 3;
  const int xo = blockIdx.x & 7;

  const float2* __restrict__ kb = ksel + bh * 8192;
  for (int i = tid; i < 8192; i += 512) Kl[i] = kb[i];

  const int xr = tid & 63;
  const int yh = tid >> 6;           // 0..7
  const int x = xo * 64 + xr;
  const float2* __restrict__ qb = qsel + bh * 8192;
  float qr[16], qi[16], ar[16], ai[16];
  sfor<16>([&](auto E) {
    constexpr int e = decltype(E)::value;
    const float2 v = qb[e * 512 + x];
    qr[e] = v.x; qi[e] = v.y;
    ar[e] = 0.f; ai[e] = 0.f;
  });
  __syncthreads();

  const int y0 = yh * 64;
  for (int y = y0; y < y0 + 64; ++y) {
    float kr[16], ki[16];
    float sr = 0.f, si = 0.f;
    sfor<16>([&](auto E) {
      constexpr int e = decltype(E)::value;
      const float2 v = Kl[e * 512 + y];      // wave-uniform -> broadcast
      kr[e] = v.x; ki[e] = v.y;
      sr = fmaf(qr[e], v.x, fmaf(-qi[e], v.y, sr));
      si = fmaf(qr[e], v.y, fmaf( qi[e], v.x, si));
    });
    // complex tanh(sr + i si) = (sinh 2a + i sin 2b) / (cosh 2a + cos 2b)
    float a2 = 2.f * sr;
    a2 = fminf(fmaxf(a2, -30.f), 30.f);
    const float b2 = 2.f * si;
    const float ea = expf(a2);
    const float ei = 1.f / ea;
    const float sh = 0.5f * (ea - ei);
    const float chp = 0.5f * (ea + ei);
    float sb, cb;
    sincosf(b2, &sb, &cb);
    const float inv = 1.f / (chp + cb);
    const float tr = sh * inv;
    const float ti = sb * inv;
    sfor<16>([&](auto E) {
      constexpr int e = decltype(E)::value;
      ar[e] = fmaf(tr, kr[e], fmaf(-ti, ki[e], ar[e]));
      ai[e] = fmaf(tr, ki[e], fmaf( ti, kr[e], ai[e]));
    });
  }
  __syncthreads();
  float* __restrict__ red = (float*)Kl;   // K dead; 16384 floats available
  if (yh) {
    const int g = yh - 1;                 // 0..6
    sfor<16>([&](auto E) {
      constexpr int e = decltype(E)::value;
      red[(g * 32 + 2 * e) * 64 + xr] = ar[e];
      red[(g * 32 + 2 * e + 1) * 64 + xr] = ai[e];
    });
  }
  __syncthreads();
  if (!yh) {
    float2* __restrict__ ob = xqkv + bh * 8192;
    sfor<16>([&](auto E) {
      constexpr int e = decltype(E)::value;
      float sr2 = ar[e], si2 = ai[e];
      #pragma unroll
      for (int g = 0; g < 7; ++g) {
        sr2 += red[(g * 32 + 2 * e) * 64 + xr];
        si2 += red[(g * 32 + 2 * e + 1) * 64 + xr];
      }
      ob[e * 512 + x] = make_float2(sr2, si2);
    });
  }
}

// ---------------------------------------------------------------------------
// Kernel 3: w-multiply + analytic canonicalized inverse transform.
// out = (1/2^22) * sum_{k} w2(k2) cos(2pi k2 n2/64) * Re[F e^{i 2pi(k0n0+k1n1)/32}]
// grid 1024 = (b,h,o); block 256. Separable: A over k2, B over k1, C over k0.
// ---------------------------------------------------------------------------
#define SCALE_OUT (1.f / 4194304.f)

__global__ __launch_bounds__(256, 2)
void k3_inv(const float2* __restrict__ xqkv, const float* __restrict__ w_re,
            const float* __restrict__ w_im, float* __restrict__ out)
{
  __shared__ float2 Fs[512];
  __shared__ float cn[64];                   // cos(2*pi*t/64)
  __shared__ float Ur[4096], Ui[4096];       // [p=k0*8+k1][n2]
  __shared__ float Vr[2048], Vi[2048];       // [k0*4+n1loc][n2], 4-n1 chunks

  const int tid = threadIdx.x;
  const int bho = blockIdx.x;
  const int o = bho & 15;
  const int h = (bho >> 4) & 7;
  const int bh = bho >> 4;                   // b*8+h

  if (tid < 64) cn[tid] = cosf((float)tid * (PI_F / 32.f));

  float cc[17];
  sfor<17>([&](auto J) { constexpr int j = decltype(J)::value;
    cc[j] = cosf((float)j * (PI_F / 32.f)); });
  #define TCOSr(T) (fold_sgn(T) * cc[fold_idx(T)])
  #define TSINr(T) (fold_sgn(((T) + 48) & 63) * cc[fold_idx(((T) + 48) & 63)])

  // F[x] = sum_e xqkv[e,x] * w[e,o,x], scaled
  const float2* __restrict__ xb = xqkv + bh * 8192;
  const float* __restrict__ wrb = w_re + ((size_t)(h * 256 + o)) * 512;
  const float* __restrict__ wib = w_im + ((size_t)(h * 256 + o)) * 512;
  for (int x = tid; x < 512; x += 256) {
    float fr = 0.f, fi = 0.f;
    sfor<16>([&](auto E) {
      constexpr int e = decltype(E)::value;
      const float2 v = xb[e * 512 + x];
      const float wr = wrb[e * 8192 + x];
      const float wi = wib[e * 8192 + x];
      fr = fmaf(v.x, wr, fmaf(-v.y, wi, fr));
      fi = fmaf(v.x, wi, fmaf( v.y, wr, fi));
    });
    Fs[x] = make_float2(fr * SCALE_OUT, fi * SCALE_OUT);
  }
  __syncthreads();

  const int n2 = tid & 63;
  const int wv = tid >> 6;

  // stage A: U[p][n2] = sum_k2 w2(k2) cos(2pi k2 n2/64) F[p*8+k2]
  #pragma unroll
  for (int i = 0; i < 16; ++i) {
    const int p = wv * 16 + i;
    float ur = 0.f, ui = 0.f;
    sfor<8>([&](auto KC) {
      constexpr int k2 = decltype(KC)::value;
      const float2 f = Fs[p * 8 + k2];       // wave-uniform broadcast
      const float cv = cn[(k2 * n2) & 63];
      const float wgt = (k2 == 0) ? cv : 2.f * cv;
      ur = fmaf(wgt, f.x, ur);
      ui = fmaf(wgt, f.y, ui);
    });
    Ur[p * 64 + n2] = ur;
    Ui[p * 64 + n2] = ui;
  }
  __syncthreads();

  // per-thread U registers for its two k0 columns
  float u_r[2][8], u_i[2][8];
  sfor<2>([&](auto JC) {
    constexpr int j = decltype(JC)::value;
    sfor<8>([&](auto KC) {
      constexpr int k1 = decltype(KC)::value;
      const int p = (wv * 2 + j) * 8 + k1;
      u_r[j][k1] = Ur[p * 64 + n2];
      u_i[j][k1] = Ui[p * 64 + n2];
    });
  });

  float* __restrict__ ob = out + (size_t)bho * 65536;

  for (int chq = 0; chq < 8; ++chq) {        // 4 n1 values per chunk
    // stage B: V[k0][n1loc][n2] = sum_k1 U * e^{+i 2pi k1 n1/32}
    sfor<2>([&](auto JC) {
      constexpr int j = decltype(JC)::value;
      const int k0 = wv * 2 + j;
      sfor<4>([&](auto LC) {
        constexpr int l = decltype(LC)::value;
        const int n1 = chq * 4 + l;
        float vr = 0.f, vi = 0.f;
        sfor<8>([&](auto KC) {
          constexpr int k1 = decltype(KC)::value;
          const int t = (2 * k1 * n1) & 63;  // wave-uniform -> broadcast reads
          const float cv = cn[t];
          const float sv = cn[(t + 48) & 63];
          vr = fmaf(u_r[j][k1], cv, fmaf(-u_i[j][k1], sv, vr));
          vi = fmaf(u_r[j][k1], sv, fmaf( u_i[j][k1], cv, vi));
        });
        Vr[(k0 * 4 + l) * 64 + n2] = vr;
        Vi[(k0 * 4 + l) * 64 + n2] = vi;
      });
    });
    __syncthreads();
    // stage C: out[n0][n1][n2] = sum_k0 Vr cos - Vi sin   (literal twiddles)
    {
      const int l = wv;
      float vrr[8], vii[8];
      sfor<8>([&](auto KC) {
        constexpr int k0 = decltype(KC)::value;
        vrr[k0] = Vr[(k0 * 4 + l) * 64 + n2];
        vii[k0] = Vi[(k0 * 4 + l) * 64 + n2];
      });
      const int n1 = chq * 4 + l;
      float* __restrict__ op = ob + n1 * 64 + n2;
      sfor<32>([&](auto NC) {
        constexpr int n0 = decltype(NC)::value;
        float acc = vrr[0];
        sfor<7>([&](auto KC) {
          constexpr int k0 = decltype(KC)::value + 1;
          constexpr int t = (2 * k0 * n0) & 63;
          acc = fmaf(vrr[k0], TCOSr(t), fmaf(-vii[k0], TSINr(t), acc));
        });
        op[n0 * 2048] = acc;
      });
    }
    __syncthreads();
  }
}

// ---------------------------------------------------------------------------
extern "C" void kernel_launch(void* const* d_in, const int* in_sizes, int n_in,
                              void* d_out, int out_size, void* d_ws, size_t ws_size,
                              hipStream_t stream)
{
  (void)in_sizes; (void)n_in; (void)out_size; (void)ws_size;
  const float* q    = (const float*)d_in[0];
  const float* k    = (const float*)d_in[1];
  const float* w_re = (const float*)d_in[2];
  const float* w_im = (const float*)d_in[3];
  float* out = (float*)d_out;

  // workspace: qsel(4MB) | ksel(4MB) | xqkv(4MB), all [bh][e][x] float2
  float2* qsel = (float2*)d_ws;
  float2* ksel = qsel + 1024 * 512;
  float2* xqkv = ksel + 1024 * 512;

  hipLaunchKernelGGL(k1_fwd_dft, dim3(2048), dim3(512), 0, stream, q, k, qsel, ksel);
  hipLaunchKernelGGL(k2_attn,    dim3(512),  dim3(512), 0, stream, qsel, ksel, xqkv);
  hipLaunchKernelGGL(k3_inv,     dim3(1024), dim3(256), 0, stream, xqkv, w_re, w_im, out);
}